// Round 17
// baseline (49.139 us; speedup 1.0000x reference)
//
#include <hip/hip_runtime.h>
#include <hip/hip_fp16.h>
#include <cmath>

#define NBINS   84
#define NFRAMES 256
#define HOP     1024
#define NB      8            // nb_samples * nb_channels
#define KP      960          // padded K (f16 columns of A / rows of B)
#define KPH     (KP/2)       // 480 cos/sin column pairs
#define GBLK    278          // number of 1024-sample output blocks
#define MROWS   (GBLK*NB)    // 2224 real rows
#define MPAD    2240         // 35*64
#define SD      23           // d-slices: max ceil(L/1024)

#define BM      64           // GEMM tile rows (R11-proven)
#define BN      32           // GEMM tile cols
#define NT      (KP/64)      // 15 K-tiles
#define TILEB   12288        // one LDS buffer: A 8KB + B 4KB
#define DEPTH   3            // pipeline depth (tiles in flight)

// builder regions (blocks of 256 threads)
#define BT_BLOCKS  1920                     // 1024 r x 480 pairs / 256
#define A_BLOCKS   4200                     // 2240 rows x 480 pairs / 256
#define S_BLOCKS   184                      // 23552 t x 2 halves / 256
#define ALL_BLOCKS (BT_BLOCKS + A_BLOCKS + S_BLOCKS)

typedef _Float16 f16x8 __attribute__((ext_vector_type(8)));
typedef float    f32x4 __attribute__((ext_vector_type(4)));

#define VMCNT(N) asm volatile("s_waitcnt vmcnt(" #N ")" ::: "memory")

__device__ __forceinline__ void gload_lds16(const void* g, void* l) {
    __builtin_amdgcn_global_load_lds(
        (__attribute__((address_space(1))) void*)(g),
        (__attribute__((address_space(3))) void*)(l), 16, 0, 0);
}

struct alignas(16) CqtArgs {
    unsigned short ct[KP];      // FIRST member, 16B-aligned: col -> k|d<<7|c<<12; 0xFFFF pad
    int   wl[NBINS];            // per-bin window length (descending)
    float omega[NBINS];         // 2*pi*f/SR
    float invL[NBINS];          // 1/wl
    int   Ktot;
};

// ---------------- fused builder: Bt + A + S, fine-grained ---------------------
__global__ __launch_bounds__(256)
void build_all(unsigned short* __restrict__ Am, unsigned short* __restrict__ Bt,
               float* __restrict__ S, const float2* __restrict__ X2, CqtArgs a) {
    const int blk = blockIdx.x;
    const int tid = threadIdx.x;
    const float TWOPI = 6.28318530717958647692f;

    if (blk < BT_BLOCKS) {
        // Bt[r][2j]=cos(w_k t)*hann, [2j+1]=sin(w_k t)*hann; ONE pair per thread
        const int idx = blk * 256 + tid;         // < 1024*480
        const int r   = idx / KPH;
        const int j   = idx - r * KPH;
        unsigned int pack = 0;
        const unsigned short rec = a.ct[2 * j];
        if (rec != 0xFFFFu) {
            const int k = rec & 0x7F, d = (rec >> 7) & 0x1F;
            const int t = (d << 10) + r;
            if (t < a.wl[k]) {
                const float tf = (float)t;
                const float w  = 0.5f - 0.5f * cosf(TWOPI * tf * a.invL[k]);
                float s, c;
                sincosf(a.omega[k] * tf, &s, &c);
                pack = (unsigned int)__half_as_ushort(__float2half(c * w))
                     | ((unsigned int)__half_as_ushort(__float2half(s * w)) << 16);
            }
        }
        *(unsigned int*)(Bt + (size_t)r * KP + 2 * j) = pack;   // coalesced 4B
    } else if (blk < BT_BLOCKS + A_BLOCKS) {
        // A[row=(g*8+b)][2j]=Re X[b,k,g-d], [2j+1]=-Im X[b,k,g-d]; ONE pair/thread
        const int idx = (blk - BT_BLOCKS) * 256 + tid;   // < 2240*480
        const int row = idx / KPH;
        const int j   = idx - row * KPH;
        unsigned int pack = 0;
        const unsigned short rec = a.ct[2 * j];
        if (row < MROWS && rec != 0xFFFFu) {
            const int k = rec & 0x7F, d = (rec >> 7) & 0x1F;
            const int g = row >> 3, b = row & 7;
            const int f = g - d;
            if (f >= 0 && f < NFRAMES) {
                const float2 x = X2[((size_t)b * NBINS + k) * NFRAMES + f];
                pack = (unsigned int)__half_as_ushort(__float2half(x.x))
                     | ((unsigned int)__half_as_ushort(__float2half(-x.y)) << 16);
            }
        }
        *(unsigned int*)(Am + (size_t)row * KP + 2 * j) = pack; // coalesced 4B
    } else {
        // S[t] = sum_k [t < wl_k] hann_k(t)^2 ; TWO lanes per t, shfl_xor combine
        const int gid = (blk - BT_BLOCKS - A_BLOCKS) * 256 + tid;  // < 2*23552
        const int t   = gid >> 1;
        const int h   = gid & 1;
        float sum = 0.f;
        const int k0 = h * (NBINS / 2);
        for (int k = k0; k < k0 + NBINS / 2; ++k) {
            if (t >= a.wl[k]) break;
            const float w = 0.5f - 0.5f * cosf(TWOPI * (float)t * a.invL[k]);
            sum += w * w;
        }
        const float tot = sum + __shfl_xor(sum, 1, 64);
        if (h == 0) S[t] = tot;
    }
}

// inverse norm: fixed-bound fully-unrolled MASKED sum (bit-identical to bounded sum)
__device__ __forceinline__ float inv_norm(const float* __restrict__ S, int g, int ncol) {
    if (g >= GBLK) return 1.0f;
    const int lo = (g > NFRAMES - 1) ? (g - (NFRAMES - 1)) : 0;
    const int hi = g < (SD - 1) ? g : (SD - 1);
    float s = 0.f;
#pragma unroll
    for (int d = 0; d < SD; ++d) {
        const float v = S[(d << 10) + ncol];
        s += (d >= lo && d <= hi) ? v : 0.0f;
    }
    return (s > 1e-10f) ? 1.0f / s : 1.0f;
}

// GEMM: C[M=2240][N=1024] = A[M][K=960] * Bt[N][K]^T, f16/f32 acc.
// 64x32 tile, 4 waves. Staging via 3-DEEP global_load_lds pipeline (LDS dest
// linear tid*16, XOR swizzle pre-applied to GLOBAL source): tile t+3 issued
// after computing t, steady-state wait vmcnt(6) -- each tile's loads get two
// compute phases to land, and 6 loads stay in flight ACROSS barriers.
// 1D grid, bijective XCD swizzle (1120=8*140).
__global__ __launch_bounds__(256)
void gemm_icqt(const unsigned short* __restrict__ Am, const unsigned short* __restrict__ Bt,
               const float* __restrict__ S, float* __restrict__ out, int length) {
    __shared__ __align__(16) char lds[DEPTH * TILEB];     // 36 KB
    const int tid = threadIdx.x;
    const int l   = tid & 63;
    const int wid = tid >> 6;
    const int wm  = wid >> 1, wn = wid & 1;

    const int bid = blockIdx.x;
    const int swz = (bid & 7) * 140 + (bid >> 3);     // XCD-chunked, bijective
    const int bm  = swz >> 5;                         // 0..34
    const int bn  = swz & 31;                         // 0..31

    // staging geometry: A 512 chunks (2/thread: q0=tid, q1=tid+256), B 256 (1/thread)
    const int q0 = tid,      q1 = tid + 256;
    const int r0 = q0 >> 3,  c0 = q0 & 7, s0 = c0 ^ (r0 & 7);
    const int r1 = q1 >> 3,  c1 = q1 & 7, s1 = c1 ^ (r1 & 7);
    const int r2 = tid >> 3, c2 = tid & 7, s2 = c2 ^ (r2 & 7);

    const char* gA0 = (const char*)Am + ((size_t)(bm * BM + r0) * KP + s0 * 8) * 2;
    const char* gA1 = (const char*)Am + ((size_t)(bm * BM + r1) * KP + s1 * 8) * 2;
    const char* gB0 = (const char*)Bt + ((size_t)(bn * BN + r2) * KP + s2 * 8) * 2;

    f32x4 acc0 = {0.f,0.f,0.f,0.f}, acc1 = {0.f,0.f,0.f,0.f};

    const int arow0 = wm * 32 + (l & 15), arow1 = arow0 + 16;
    const int brow  = wn * 16 + (l & 15);
    const int kq = l >> 4;

    // prologue: tiles 0..2 -> buffers 0..2 (9 loads/thread in flight)
#pragma unroll
    for (int t = 0; t < DEPTH; ++t) {
        char* bA = lds + t * TILEB;
        char* bB = bA + 8192;
        gload_lds16(gA0 + t * 128, bA + tid * 16);
        gload_lds16(gA1 + t * 128, bA + 4096 + tid * 16);
        gload_lds16(gB0 + t * 128, bB + tid * 16);
    }

#pragma unroll
    for (int t = 0; t < NT; ++t) {
        const int buf = t - (t / DEPTH) * DEPTH;           // t % 3, static under unroll
        char* bA = lds + buf * TILEB;
        char* bB = bA + 8192;
        if (t < NT - 2)       { VMCNT(6); }                // tile t's 3 loads done
        else if (t == NT - 2) { VMCNT(3); }
        else                  { VMCNT(0); }
        __builtin_amdgcn_s_barrier();                      // raw: loads stay in flight
#pragma unroll
        for (int ks = 0; ks < 2; ++ks) {
            const int kb = ks * 4 + kq;
            f16x8 a0 = *(const f16x8*)(bA + arow0 * 128 + ((kb ^ (arow0 & 7)) << 4));
            f16x8 a1 = *(const f16x8*)(bA + arow1 * 128 + ((kb ^ (arow1 & 7)) << 4));
            f16x8 b0 = *(const f16x8*)(bB + brow  * 128 + ((kb ^ (brow  & 7)) << 4));
            acc0 = __builtin_amdgcn_mfma_f32_16x16x32_f16(a0, b0, acc0, 0, 0, 0);
            acc1 = __builtin_amdgcn_mfma_f32_16x16x32_f16(a1, b0, acc1, 0, 0, 0);
        }
        if (t + DEPTH < NT) {
            __builtin_amdgcn_s_barrier();                  // all waves done reading buf
            const int off = (t + DEPTH) * 128;             // 64 cols * 2B per tile
            gload_lds16(gA0 + off, bA + tid * 16);
            gload_lds16(gA1 + off, bA + 4096 + tid * 16);
            gload_lds16(gB0 + off, bB + tid * 16);
        }
    }

    // epilogue: C/D layout col=l&15, row=(l>>4)*4+reg. Per lane: 2 g's, 1 ncol.
    const int mbase = bm * BM + wm * 32;
    const int ncol  = bn * BN + wn * 16 + (l & 15);
    const int g0    = (mbase >> 3) + (kq >> 1);
    const float inv0 = inv_norm(S, g0,     ncol);
    const float inv1 = inv_norm(S, g0 + 2, ncol);

#pragma unroll
    for (int mi = 0; mi < 2; ++mi) {
        const f32x4 v    = mi ? acc1 : acc0;
        const float invv = mi ? inv1 : inv0;
#pragma unroll
        for (int reg = 0; reg < 4; ++reg) {
            const int mrow = mbase + mi * 16 + kq * 4 + reg;
            if (mrow < MROWS) {
                const int g = mrow >> 3, b = mrow & 7;
                const int p = (g << 10) + ncol;
                if (p < length)
                    out[(size_t)b * length + p] = v[reg] * invv;
            }
        }
    }
}

// Last-resort fallback (ws too small): on-the-fly trig gather.
__global__ void icqt_gather_fallback(const float* __restrict__ X, float* __restrict__ out,
                                     CqtArgs a, int length) {
    const int p = blockIdx.x * blockDim.x + threadIdx.x;
    if (p >= length) return;
    float acc[NB];
#pragma unroll
    for (int b = 0; b < NB; ++b) acc[b] = 0.0f;
    float nrm = 0.0f;
    int fhi = p >> 10;
    if (fhi > NFRAMES - 1) fhi = NFRAMES - 1;
    const float2* X2 = reinterpret_cast<const float2*>(X);
    for (int k = 0; k < NBINS; ++k) {
        const int L = a.wl[k];
        int flo = (p - L + HOP) >> 10;
        if (flo < 0) flo = 0;
        for (int f = flo; f <= fhi; ++f) {
            const int t = p - (f << 10);
            if (t < L) {
                float tf = (float)t;
                float ang = a.omega[k] * tf;
                float s = sinf(ang), c = cosf(ang);
                float w = 0.5f - 0.5f * cosf(6.28318530717958647692f * tf * a.invL[k]);
                float bre = c * w, bim = s * w;
                nrm += w * w;
                const int base = k * NFRAMES + f;
#pragma unroll
                for (int b = 0; b < NB; ++b) {
                    float2 cv = X2[(size_t)b * (NBINS * NFRAMES) + base];
                    acc[b] += cv.x * bre - cv.y * bim;
                }
            }
        }
    }
    const float inv = 1.0f / ((nrm > 1e-10f) ? nrm : 1.0f);
#pragma unroll
    for (int b = 0; b < NB; ++b)
        out[(size_t)b * length + p] = acc[b] * inv;
}

extern "C" void kernel_launch(void* const* d_in, const int* in_sizes, int n_in,
                              void* d_out, int out_size, void* d_ws, size_t ws_size,
                              hipStream_t stream) {
    // Host geometry (deterministic; np.round = banker's via nearbyint)
    CqtArgs a;
    int cb[NBINS];
    const double SR = 44100.0;
    const double Q  = 1.0 / (std::exp2(1.0 / 12.0) - 1.0);
    int Ktot = 0;
    for (int k = 0; k < NBINS; ++k) {
        double f = 32.7 * std::exp2((double)k / 12.0);
        int L = (int)std::nearbyint(Q * SR / f);
        a.wl[k]    = L;
        cb[k]      = Ktot;
        a.omega[k] = (float)(2.0 * 3.14159265358979323846 * f / SR);
        a.invL[k]  = (float)(1.0 / (double)L);
        Ktot += 2 * ((L + 1023) / 1024);
    }
    a.Ktot = Ktot;
    for (int col = 0; col < KP; ++col) a.ct[col] = 0xFFFF;
    if (Ktot <= KP) {
        for (int k = 0; k < NBINS; ++k) {
            const int D2 = 2 * ((a.wl[k] + 1023) / 1024);
            for (int j = 0; j < D2; ++j)
                a.ct[cb[k] + j] = (unsigned short)(k | ((j >> 1) << 7) | ((j & 1) << 12));
        }
    }

    const int length = out_size / NB;            // 283800
    const float* X = (const float*)d_in[0];
    float* out     = (float*)d_out;

    // ws layout: [ A f16 MPADxKP ][ Bt f16 1024xKP ][ S f32 23*1024 ]
    const size_t offA = 0;
    const size_t szA  = (size_t)MPAD * KP * 2;           // 4,300,800
    const size_t offB = offA + szA;
    const size_t szB  = (size_t)1024 * KP * 2;           // 1,966,080
    const size_t offS = offB + szB;
    const size_t szS  = (size_t)SD * 1024 * 4;           //    94,208
    const size_t need = offS + szS;

    if (Ktot > KP || a.wl[0] > SD * 1024 || ws_size < need) {
        const int blocks = (length + 255) / 256;
        icqt_gather_fallback<<<blocks, 256, 0, stream>>>(X, out, a, length);
        return;
    }

    unsigned short* Am = (unsigned short*)((char*)d_ws + offA);
    unsigned short* Bt = (unsigned short*)((char*)d_ws + offB);
    float*          S  = (float*)((char*)d_ws + offS);

    build_all<<<dim3(ALL_BLOCKS), 256, 0, stream>>>(Am, Bt, S, (const float2*)X, a);
    gemm_icqt<<<dim3((MPAD / BM) * (1024 / BN)), 256, 0, stream>>>(Am, Bt, S, out, length);
}

// Round 18
// 43.396 us; speedup vs baseline: 1.1323x; 1.1323x over previous
//
#include <hip/hip_runtime.h>
#include <hip/hip_fp16.h>
#include <cmath>

#define NBINS   84
#define NFRAMES 256
#define HOP     1024
#define NB      8            // nb_samples * nb_channels
#define KP      960          // padded K (f16 columns of A / rows of B)
#define KPH     (KP/2)       // 480 cos/sin column pairs
#define GBLK    278          // number of 1024-sample output blocks
#define MROWS   (GBLK*NB)    // 2224 real rows
#define MPAD    2240         // 35*64
#define SD      23           // d-slices: max ceil(L/1024)

#define BM      64           // GEMM tile rows (R11-proven)
#define BN      32           // GEMM tile cols
#define NT      (KP/64)      // 15 K-tiles
#define TILEB   12288        // one LDS buffer: A 8KB + B 4KB  (DEPTH=2 -> 24KB, 6 blk/CU)

// builder regions (blocks of 256 threads)
#define BT_BLOCKS  1920                     // 1024 r x 480 pairs / 256
#define A_BLOCKS   4200                     // 2240 rows x 480 pairs / 256
#define S_BLOCKS   184                      // 23552 t x 2 halves / 256
#define ALL_BLOCKS (BT_BLOCKS + A_BLOCKS + S_BLOCKS)

typedef _Float16 f16x8 __attribute__((ext_vector_type(8)));
typedef float    f32x4 __attribute__((ext_vector_type(4)));

#define VMCNT(N) asm volatile("s_waitcnt vmcnt(" #N ")" ::: "memory")

__device__ __forceinline__ void gload_lds16(const void* g, void* l) {
    __builtin_amdgcn_global_load_lds(
        (__attribute__((address_space(1))) void*)(g),
        (__attribute__((address_space(3))) void*)(l), 16, 0, 0);
}

struct alignas(16) CqtArgs {
    unsigned short ct[KP];      // FIRST member, 16B-aligned: col -> k|d<<7|c<<12; 0xFFFF pad
    int   wl[NBINS];            // per-bin window length (descending)
    float omega[NBINS];         // 2*pi*f/SR
    float invL[NBINS];          // 1/wl
    int   Ktot;
};

// ---------------- fused builder: Bt + A + S, fine-grained ---------------------
__global__ __launch_bounds__(256)
void build_all(unsigned short* __restrict__ Am, unsigned short* __restrict__ Bt,
               float* __restrict__ S, const float2* __restrict__ X2, CqtArgs a) {
    const int blk = blockIdx.x;
    const int tid = threadIdx.x;
    const float TWOPI = 6.28318530717958647692f;

    if (blk < BT_BLOCKS) {
        // Bt[r][2j]=cos(w_k t)*hann, [2j+1]=sin(w_k t)*hann; ONE pair per thread
        const int idx = blk * 256 + tid;         // < 1024*480
        const int r   = idx / KPH;
        const int j   = idx - r * KPH;
        unsigned int pack = 0;
        const unsigned short rec = a.ct[2 * j];
        if (rec != 0xFFFFu) {
            const int k = rec & 0x7F, d = (rec >> 7) & 0x1F;
            const int t = (d << 10) + r;
            if (t < a.wl[k]) {
                const float tf = (float)t;
                const float w  = 0.5f - 0.5f * cosf(TWOPI * tf * a.invL[k]);
                float s, c;
                sincosf(a.omega[k] * tf, &s, &c);
                pack = (unsigned int)__half_as_ushort(__float2half(c * w))
                     | ((unsigned int)__half_as_ushort(__float2half(s * w)) << 16);
            }
        }
        *(unsigned int*)(Bt + (size_t)r * KP + 2 * j) = pack;   // coalesced 4B
    } else if (blk < BT_BLOCKS + A_BLOCKS) {
        // A[row=(g*8+b)][2j]=Re X[b,k,g-d], [2j+1]=-Im X[b,k,g-d]; ONE pair/thread
        const int idx = (blk - BT_BLOCKS) * 256 + tid;   // < 2240*480
        const int row = idx / KPH;
        const int j   = idx - row * KPH;
        unsigned int pack = 0;
        const unsigned short rec = a.ct[2 * j];
        if (row < MROWS && rec != 0xFFFFu) {
            const int k = rec & 0x7F, d = (rec >> 7) & 0x1F;
            const int g = row >> 3, b = row & 7;
            const int f = g - d;
            if (f >= 0 && f < NFRAMES) {
                const float2 x = X2[((size_t)b * NBINS + k) * NFRAMES + f];
                pack = (unsigned int)__half_as_ushort(__float2half(x.x))
                     | ((unsigned int)__half_as_ushort(__float2half(-x.y)) << 16);
            }
        }
        *(unsigned int*)(Am + (size_t)row * KP + 2 * j) = pack; // coalesced 4B
    } else {
        // S[t] = sum_k [t < wl_k] hann_k(t)^2 ; TWO lanes per t, shfl_xor combine
        const int gid = (blk - BT_BLOCKS - A_BLOCKS) * 256 + tid;  // < 2*23552
        const int t   = gid >> 1;
        const int h   = gid & 1;
        float sum = 0.f;
        const int k0 = h * (NBINS / 2);
        for (int k = k0; k < k0 + NBINS / 2; ++k) {
            if (t >= a.wl[k]) break;
            const float w = 0.5f - 0.5f * cosf(TWOPI * (float)t * a.invL[k]);
            sum += w * w;
        }
        const float tot = sum + __shfl_xor(sum, 1, 64);
        if (h == 0) S[t] = tot;
    }
}

// inverse norm: fixed-bound fully-unrolled MASKED sum (bit-identical to bounded sum)
__device__ __forceinline__ float inv_norm(const float* __restrict__ S, int g, int ncol) {
    if (g >= GBLK) return 1.0f;
    const int lo = (g > NFRAMES - 1) ? (g - (NFRAMES - 1)) : 0;
    const int hi = g < (SD - 1) ? g : (SD - 1);
    float s = 0.f;
#pragma unroll
    for (int d = 0; d < SD; ++d) {
        const float v = S[(d << 10) + ncol];
        s += (d >= lo && d <= hi) ? v : 0.0f;
    }
    return (s > 1e-10f) ? 1.0f / s : 1.0f;
}

// GEMM (R16 structure + T5 setprio): 64x32 tile, 4 waves, double-buffered
// global_load_lds staging (LDS dest linear tid*16, XOR swizzle pre-applied on
// GLOBAL source), counted vmcnt(3) + raw s_barrier (loads in flight across
// barriers), s_setprio(1) around the ds_read+MFMA cluster so MFMA-phase waves
// win CU arbitration over staging-phase waves of co-resident blocks.
__global__ __launch_bounds__(256)
void gemm_icqt(const unsigned short* __restrict__ Am, const unsigned short* __restrict__ Bt,
               const float* __restrict__ S, float* __restrict__ out, int length) {
    __shared__ __align__(16) char lds[2 * TILEB];     // 24 KB
    const int tid = threadIdx.x;
    const int l   = tid & 63;
    const int wid = tid >> 6;
    const int wm  = wid >> 1, wn = wid & 1;

    const int bid = blockIdx.x;
    const int swz = (bid & 7) * 140 + (bid >> 3);     // XCD-chunked, bijective
    const int bm  = swz >> 5;                         // 0..34
    const int bn  = swz & 31;                         // 0..31

    // staging geometry: A 512 chunks (2/thread), B 256 (1/thread)
    const int q0 = tid,      q1 = tid + 256;
    const int r0 = q0 >> 3,  c0 = q0 & 7, s0 = c0 ^ (r0 & 7);
    const int r1 = q1 >> 3,  c1 = q1 & 7, s1 = c1 ^ (r1 & 7);
    const int r2 = tid >> 3, c2 = tid & 7, s2 = c2 ^ (r2 & 7);

    const char* gA0 = (const char*)Am + ((size_t)(bm * BM + r0) * KP + s0 * 8) * 2;
    const char* gA1 = (const char*)Am + ((size_t)(bm * BM + r1) * KP + s1 * 8) * 2;
    const char* gB0 = (const char*)Bt + ((size_t)(bn * BN + r2) * KP + s2 * 8) * 2;

    f32x4 acc0 = {0.f,0.f,0.f,0.f}, acc1 = {0.f,0.f,0.f,0.f};

    const int arow0 = wm * 32 + (l & 15), arow1 = arow0 + 16;
    const int brow  = wn * 16 + (l & 15);
    const int kq = l >> 4;

    // prologue: tiles 0,1 -> buffers 0,1 (6 loads/thread in flight)
    {
        char* bA = lds;            char* bB = lds + 8192;
        gload_lds16(gA0,       bA + tid * 16);
        gload_lds16(gA1,       bA + 4096 + tid * 16);
        gload_lds16(gB0,       bB + tid * 16);
        char* cA = lds + TILEB;    char* cB = cA + 8192;
        gload_lds16(gA0 + 128, cA + tid * 16);
        gload_lds16(gA1 + 128, cA + 4096 + tid * 16);
        gload_lds16(gB0 + 128, cB + tid * 16);
    }

#pragma unroll
    for (int t = 0; t < NT; ++t) {
        char* bA = lds + (t & 1) * TILEB;
        char* bB = bA + 8192;
        if (t + 1 < NT) { VMCNT(3); } else { VMCNT(0); }   // static after unroll
        __builtin_amdgcn_s_barrier();                      // raw: no vmcnt(0) drain
        __builtin_amdgcn_s_setprio(1);                     // T5: favor compute-phase wave
#pragma unroll
        for (int ks = 0; ks < 2; ++ks) {
            const int kb = ks * 4 + kq;
            f16x8 a0 = *(const f16x8*)(bA + arow0 * 128 + ((kb ^ (arow0 & 7)) << 4));
            f16x8 a1 = *(const f16x8*)(bA + arow1 * 128 + ((kb ^ (arow1 & 7)) << 4));
            f16x8 b0 = *(const f16x8*)(bB + brow  * 128 + ((kb ^ (brow  & 7)) << 4));
            acc0 = __builtin_amdgcn_mfma_f32_16x16x32_f16(a0, b0, acc0, 0, 0, 0);
            acc1 = __builtin_amdgcn_mfma_f32_16x16x32_f16(a1, b0, acc1, 0, 0, 0);
        }
        __builtin_amdgcn_s_setprio(0);
        if (t + 2 < NT) {
            __builtin_amdgcn_s_barrier();                  // all waves done reading bA/bB
            const int off = (t + 2) * 128;                 // 64 cols * 2B per tile
            gload_lds16(gA0 + off, bA + tid * 16);
            gload_lds16(gA1 + off, bA + 4096 + tid * 16);
            gload_lds16(gB0 + off, bB + tid * 16);
        }
    }

    // epilogue: C/D layout col=l&15, row=(l>>4)*4+reg. Per lane: 2 g's, 1 ncol.
    const int mbase = bm * BM + wm * 32;
    const int ncol  = bn * BN + wn * 16 + (l & 15);
    const int g0    = (mbase >> 3) + (kq >> 1);
    const float inv0 = inv_norm(S, g0,     ncol);
    const float inv1 = inv_norm(S, g0 + 2, ncol);

#pragma unroll
    for (int mi = 0; mi < 2; ++mi) {
        const f32x4 v    = mi ? acc1 : acc0;
        const float invv = mi ? inv1 : inv0;
#pragma unroll
        for (int reg = 0; reg < 4; ++reg) {
            const int mrow = mbase + mi * 16 + kq * 4 + reg;
            if (mrow < MROWS) {
                const int g = mrow >> 3, b = mrow & 7;
                const int p = (g << 10) + ncol;
                if (p < length)
                    out[(size_t)b * length + p] = v[reg] * invv;
            }
        }
    }
}

// Last-resort fallback (ws too small): on-the-fly trig gather.
__global__ void icqt_gather_fallback(const float* __restrict__ X, float* __restrict__ out,
                                     CqtArgs a, int length) {
    const int p = blockIdx.x * blockDim.x + threadIdx.x;
    if (p >= length) return;
    float acc[NB];
#pragma unroll
    for (int b = 0; b < NB; ++b) acc[b] = 0.0f;
    float nrm = 0.0f;
    int fhi = p >> 10;
    if (fhi > NFRAMES - 1) fhi = NFRAMES - 1;
    const float2* X2 = reinterpret_cast<const float2*>(X);
    for (int k = 0; k < NBINS; ++k) {
        const int L = a.wl[k];
        int flo = (p - L + HOP) >> 10;
        if (flo < 0) flo = 0;
        for (int f = flo; f <= fhi; ++f) {
            const int t = p - (f << 10);
            if (t < L) {
                float tf = (float)t;
                float ang = a.omega[k] * tf;
                float s = sinf(ang), c = cosf(ang);
                float w = 0.5f - 0.5f * cosf(6.28318530717958647692f * tf * a.invL[k]);
                float bre = c * w, bim = s * w;
                nrm += w * w;
                const int base = k * NFRAMES + f;
#pragma unroll
                for (int b = 0; b < NB; ++b) {
                    float2 cv = X2[(size_t)b * (NBINS * NFRAMES) + base];
                    acc[b] += cv.x * bre - cv.y * bim;
                }
            }
        }
    }
    const float inv = 1.0f / ((nrm > 1e-10f) ? nrm : 1.0f);
#pragma unroll
    for (int b = 0; b < NB; ++b)
        out[(size_t)b * length + p] = acc[b] * inv;
}

extern "C" void kernel_launch(void* const* d_in, const int* in_sizes, int n_in,
                              void* d_out, int out_size, void* d_ws, size_t ws_size,
                              hipStream_t stream) {
    // Host geometry (deterministic; np.round = banker's via nearbyint)
    CqtArgs a;
    int cb[NBINS];
    const double SR = 44100.0;
    const double Q  = 1.0 / (std::exp2(1.0 / 12.0) - 1.0);
    int Ktot = 0;
    for (int k = 0; k < NBINS; ++k) {
        double f = 32.7 * std::exp2((double)k / 12.0);
        int L = (int)std::nearbyint(Q * SR / f);
        a.wl[k]    = L;
        cb[k]      = Ktot;
        a.omega[k] = (float)(2.0 * 3.14159265358979323846 * f / SR);
        a.invL[k]  = (float)(1.0 / (double)L);
        Ktot += 2 * ((L + 1023) / 1024);
    }
    a.Ktot = Ktot;
    for (int col = 0; col < KP; ++col) a.ct[col] = 0xFFFF;
    if (Ktot <= KP) {
        for (int k = 0; k < NBINS; ++k) {
            const int D2 = 2 * ((a.wl[k] + 1023) / 1024);
            for (int j = 0; j < D2; ++j)
                a.ct[cb[k] + j] = (unsigned short)(k | ((j >> 1) << 7) | ((j & 1) << 12));
        }
    }

    const int length = out_size / NB;            // 283800
    const float* X = (const float*)d_in[0];
    float* out     = (float*)d_out;

    // ws layout: [ A f16 MPADxKP ][ Bt f16 1024xKP ][ S f32 23*1024 ]
    const size_t offA = 0;
    const size_t szA  = (size_t)MPAD * KP * 2;           // 4,300,800
    const size_t offB = offA + szA;
    const size_t szB  = (size_t)1024 * KP * 2;           // 1,966,080
    const size_t offS = offB + szB;
    const size_t szS  = (size_t)SD * 1024 * 4;           //    94,208
    const size_t need = offS + szS;

    if (Ktot > KP || a.wl[0] > SD * 1024 || ws_size < need) {
        const int blocks = (length + 255) / 256;
        icqt_gather_fallback<<<blocks, 256, 0, stream>>>(X, out, a, length);
        return;
    }

    unsigned short* Am = (unsigned short*)((char*)d_ws + offA);
    unsigned short* Bt = (unsigned short*)((char*)d_ws + offB);
    float*          S  = (float*)((char*)d_ws + offS);

    build_all<<<dim3(ALL_BLOCKS), 256, 0, stream>>>(Am, Bt, S, (const float2*)X, a);
    gemm_icqt<<<dim3((MPAD / BM) * (1024 / BN)), 256, 0, stream>>>(Am, Bt, S, out, length);
}